// Round 1
// baseline (363.778 us; speedup 1.0000x reference)
//
#include <hip/hip_runtime.h>
#include <hip/hip_bf16.h>

typedef __attribute__((ext_vector_type(8))) __bf16 bf16x8;
typedef __attribute__((ext_vector_type(4))) float f32x4;

#define NB 32768
#define HDIM 512
#define KDIM 1024

struct WPtrs { const float* wi[4]; const float* wh[4]; };
struct BPtrs { const float* bi[4]; const float* bh[4]; };

// ---------------- prep: pack W^T (bf16, gate-interleaved rows) ----------------
// Wt row p = (n'>>5)*128 + g*32 + (n'&31), cols = k (0..1023, k<512 from w_i, else w_h)
__global__ void pack_w_kernel(WPtrs p, __bf16* __restrict__ Wt) {
  __shared__ float tile[64][65];
  const int kt = blockIdx.x;   // 16 k-tiles of 64
  const int nt = blockIdx.y;   // 8 n'-tiles of 64
  const int g  = blockIdx.z;   // 4 gates (i,f,g,o)
  const int k0 = kt * 64, n0 = nt * 64;
  const float* src = (k0 < 512) ? p.wi[g] : p.wh[g];
  const int k0l = (k0 < 512) ? k0 : (k0 - 512);
  const int tid = threadIdx.x;
  const int rr = tid >> 6;   // 0..3
  const int cc = tid & 63;
#pragma unroll
  for (int pp = 0; pp < 16; ++pp) {
    int kk = pp * 4 + rr;
    tile[kk][cc] = src[(size_t)(k0l + kk) * 512 + (n0 + cc)];
  }
  __syncthreads();
#pragma unroll
  for (int pp = 0; pp < 16; ++pp) {
    int nn = pp * 4 + rr;
    int np = n0 + nn;
    int prow = ((np >> 5) << 7) + g * 32 + (np & 31);
    Wt[(size_t)prow * KDIM + (k0 + cc)] = (__bf16)tile[cc][nn];
  }
}

__global__ void pack_bias_kernel(BPtrs p, float* __restrict__ bias) {
  int idx = blockIdx.x * 256 + threadIdx.x;  // 0..2047
  int g = idx >> 9, np = idx & 511;
  bias[idx] = p.bi[g][np] + p.bh[g][np];
}

// ---------------- main fused GEMM + LSTM epilogue ----------------
__device__ __forceinline__ float fsigmoid(float x) {
  return 1.0f / (1.0f + __expf(-x));
}
__device__ __forceinline__ float ftanh(float x) {
  return 2.0f / (1.0f + __expf(-2.0f * x)) - 1.0f;
}
__device__ __forceinline__ bf16x8 pack8(float4 a, float4 b) {
  bf16x8 r;
  r[0] = (__bf16)a.x; r[1] = (__bf16)a.y; r[2] = (__bf16)a.z; r[3] = (__bf16)a.w;
  r[4] = (__bf16)b.x; r[5] = (__bf16)b.y; r[6] = (__bf16)b.z; r[7] = (__bf16)b.w;
  return r;
}
__device__ __forceinline__ void gll16(const void* g, void* l) {
  __builtin_amdgcn_global_load_lds(
      (const __attribute__((address_space(1))) void*)g,
      (__attribute__((address_space(3))) void*)l, 16, 0, 0);
}

__global__ __launch_bounds__(256) void lstm_gemm(
    const float* __restrict__ xin, const float* __restrict__ hin,
    const float* __restrict__ cin, const __bf16* __restrict__ Wt,
    const float* __restrict__ bias, float* __restrict__ out) {
  __shared__ alignas(16) __bf16 Alds[2][128 * 32];
  __shared__ alignas(16) __bf16 Blds[2][128 * 32];

  const int tid = threadIdx.x;
  const int w = tid >> 6;
  const int lane = tid & 63;
  const int bid = blockIdx.x;
  const int bm = bid >> 4;   // 256 row-blocks of 128
  const int bn = bid & 15;   // 16 col-blocks (32 H-cols x 4 gates)

  f32x4 acc[2][8];
#pragma unroll
  for (int m = 0; m < 2; ++m)
#pragma unroll
    for (int n = 0; n < 8; ++n) acc[m][n] = (f32x4){0.f, 0.f, 0.f, 0.f};

  const int ra = tid >> 2;  // 0..63 (tile row)
  const int q = tid & 3;    // 8-float quad within BK=32
  const size_t arow0 = (size_t)(bm * 128 + ra) * 512;
  const size_t arow1 = (size_t)(bm * 128 + ra + 64) * 512;
  const int fc = lane & 15;
  const int fg = lane >> 4;
  const int kg8 = fg * 8;

  // ---- prologue: stage k-tile 0 into buffer 0 ----
  {
    const int k = q * 8;  // kt=0 -> k<512 -> xin
    float4 v0 = *(const float4*)(xin + arow0 + k);
    float4 v1 = *(const float4*)(xin + arow0 + k + 4);
    float4 v2 = *(const float4*)(xin + arow1 + k);
    float4 v3 = *(const float4*)(xin + arow1 + k + 4);
    *(bf16x8*)&Alds[0][ra * 32 + q * 8] = pack8(v0, v1);
    *(bf16x8*)&Alds[0][(ra + 64) * 32 + q * 8] = pack8(v2, v3);
    const __bf16* bs0 = Wt + (size_t)(bn * 128 + ra) * KDIM + q * 8;
    gll16(bs0, (void*)&Blds[0][w * 512]);
    gll16(bs0 + (size_t)64 * KDIM, (void*)&Blds[0][2048 + w * 512]);
  }
  __syncthreads();

  // ---- main K loop: 32 steps of BK=32 ----
#pragma unroll 2
  for (int kt = 0; kt < 32; ++kt) {
    const int cur = kt & 1;
    const int nxt = cur ^ 1;
    float4 v0, v1, v2, v3;
    const bool pf = (kt < 31);
    if (pf) {
      const int kg = (kt + 1) * 32 + q * 8;
      const float* srcb = (kg < 512) ? (xin + kg) : (hin + (kg - 512));
      v0 = *(const float4*)(srcb + arow0);
      v1 = *(const float4*)(srcb + arow0 + 4);
      v2 = *(const float4*)(srcb + arow1);
      v3 = *(const float4*)(srcb + arow1 + 4);
      const __bf16* bs0 =
          Wt + (size_t)(bn * 128 + ra) * KDIM + (kt + 1) * 32 + q * 8;
      gll16(bs0, (void*)&Blds[nxt][w * 512]);
      gll16(bs0 + (size_t)64 * KDIM, (void*)&Blds[nxt][2048 + w * 512]);
    }
    // compute on buffer cur
    bf16x8 af0 = *(const bf16x8*)&Alds[cur][(w * 32 + fc) * 32 + kg8];
    bf16x8 af1 = *(const bf16x8*)&Alds[cur][(w * 32 + 16 + fc) * 32 + kg8];
#pragma unroll
    for (int nf = 0; nf < 8; ++nf) {
      bf16x8 bfrag = *(const bf16x8*)&Blds[cur][(nf * 16 + fc) * 32 + kg8];
      acc[0][nf] =
          __builtin_amdgcn_mfma_f32_16x16x32_bf16(af0, bfrag, acc[0][nf], 0, 0, 0);
      acc[1][nf] =
          __builtin_amdgcn_mfma_f32_16x16x32_bf16(af1, bfrag, acc[1][nf], 0, 0, 0);
    }
    if (pf) {
      *(bf16x8*)&Alds[nxt][ra * 32 + q * 8] = pack8(v0, v1);
      *(bf16x8*)&Alds[nxt][(ra + 64) * 32 + q * 8] = pack8(v2, v3);
    }
    __syncthreads();
  }

  // ---- fused LSTM epilogue ----
  // acc[m][g*2+nn][j]: row = bm*128 + w*32 + m*16 + fg*4 + j, H-col = bn*32 + nn*16 + fc
  const size_t couts = (size_t)NB * HDIM;
#pragma unroll
  for (int nn = 0; nn < 2; ++nn) {
    const int np = bn * 32 + nn * 16 + fc;
    const float bi = bias[np];
    const float bff = bias[512 + np];
    const float bg = bias[1024 + np];
    const float bo = bias[1536 + np];
#pragma unroll
    for (int m = 0; m < 2; ++m) {
      const int rbase = bm * 128 + w * 32 + m * 16 + fg * 4;
#pragma unroll
      for (int j = 0; j < 4; ++j) {
        const size_t off = (size_t)(rbase + j) * HDIM + np;
        float i_ = fsigmoid(acc[m][nn][j] + bi);
        float f_ = fsigmoid(acc[m][2 + nn][j] + bff);
        float g_ = fsigmoid(acc[m][4 + nn][j] + bg);
        float o_ = fsigmoid(acc[m][6 + nn][j] + bo);
        float cp = f_ * cin[off] + i_ * g_;
        float hp = o_ * ftanh(cp);
        out[off] = hp;
        out[couts + off] = cp;
      }
    }
  }
}

extern "C" void kernel_launch(void* const* d_in, const int* in_sizes, int n_in,
                              void* d_out, int out_size, void* d_ws,
                              size_t ws_size, hipStream_t stream) {
  const float* xin = (const float*)d_in[0];
  const float* hin = (const float*)d_in[1];
  const float* cin = (const float*)d_in[2];
  // dict order: 3 w_ii, 4 w_hi, 5 b_ii, 6 b_hi, 7 w_if, 8 w_hf, 9 b_if, 10 b_hf,
  //             11 w_ig, 12 w_hg, 13 b_ig, 14 b_hg, 15 w_io, 16 w_ho, 17 b_io, 18 b_ho
  WPtrs wp;
  wp.wi[0] = (const float*)d_in[3];
  wp.wi[1] = (const float*)d_in[7];
  wp.wi[2] = (const float*)d_in[11];
  wp.wi[3] = (const float*)d_in[15];
  wp.wh[0] = (const float*)d_in[4];
  wp.wh[1] = (const float*)d_in[8];
  wp.wh[2] = (const float*)d_in[12];
  wp.wh[3] = (const float*)d_in[16];
  BPtrs bp;
  bp.bi[0] = (const float*)d_in[5];
  bp.bi[1] = (const float*)d_in[9];
  bp.bi[2] = (const float*)d_in[13];
  bp.bi[3] = (const float*)d_in[17];
  bp.bh[0] = (const float*)d_in[6];
  bp.bh[1] = (const float*)d_in[10];
  bp.bh[2] = (const float*)d_in[14];
  bp.bh[3] = (const float*)d_in[18];

  __bf16* Wt = (__bf16*)d_ws;                               // 2048*1024*2 = 4 MiB
  float* bias = (float*)((char*)d_ws + (size_t)2048 * 1024 * 2);  // 8 KiB

  pack_w_kernel<<<dim3(16, 8, 4), 256, 0, stream>>>(wp, Wt);
  pack_bias_kernel<<<8, 256, 0, stream>>>(bp, bias);
  lstm_gemm<<<4096, 256, 0, stream>>>(xin, hin, cin, Wt, bias, (float*)d_out);
}

// Round 2
// 214.218 us; speedup vs baseline: 1.6982x; 1.6982x over previous
//
#include <hip/hip_runtime.h>
#include <hip/hip_bf16.h>

typedef __attribute__((ext_vector_type(8))) __bf16 bf16x8;
typedef __attribute__((ext_vector_type(4))) float f32x4;

#define NB 32768
#define HDIM 512
#define KDIM 1024

struct WPtrs { const float* wi[4]; const float* wh[4]; };
struct BPtrs { const float* bi[4]; const float* bh[4]; };

__device__ __forceinline__ float fsigmoid(float x) {
  return 1.0f / (1.0f + __expf(-x));
}
__device__ __forceinline__ float ftanh(float x) {
  return 2.0f / (1.0f + __expf(-2.0f * x)) - 1.0f;
}
__device__ __forceinline__ bf16x8 pack8(float4 a, float4 b) {
  bf16x8 r;
  r[0] = (__bf16)a.x; r[1] = (__bf16)a.y; r[2] = (__bf16)a.z; r[3] = (__bf16)a.w;
  r[4] = (__bf16)b.x; r[5] = (__bf16)b.y; r[6] = (__bf16)b.z; r[7] = (__bf16)b.w;
  return r;
}
__device__ __forceinline__ void gll16(const void* g, void* l) {
  __builtin_amdgcn_global_load_lds(
      (const __attribute__((address_space(1))) void*)g,
      (__attribute__((address_space(3))) void*)l, 16, 0, 0);
}
#define MFMA16(A, B, C) \
  C = __builtin_amdgcn_mfma_f32_16x16x32_bf16(A, B, C, 0, 0, 0)

// ====================== shared prep ======================
__global__ void pack_bias_kernel(BPtrs p, float* __restrict__ bias) {
  int idx = blockIdx.x * 256 + threadIdx.x;  // 0..2047
  int g = idx >> 9, np = idx & 511;
  bias[idx] = p.bi[g][np] + p.bh[g][np];
}

// ====================== v2 prep ======================
// A = [x | h] -> bf16 [32768][1024]
__global__ void conv_a_kernel(const float* __restrict__ x,
                              const float* __restrict__ h,
                              __bf16* __restrict__ Abf) {
  const size_t N8 = (size_t)NB * KDIM / 8;
  for (size_t i = (size_t)blockIdx.x * blockDim.x + threadIdx.x; i < N8;
       i += (size_t)gridDim.x * blockDim.x) {
    size_t e = i * 8;
    int k = (int)(e & (KDIM - 1));
    size_t r = e >> 10;
    const float* s = (k < 512) ? (x + r * 512 + k) : (h + r * 512 + (k - 512));
    float4 v0 = *(const float4*)s;
    float4 v1 = *(const float4*)(s + 4);
    *(bf16x8*)(Abf + e) = pack8(v0, v1);
  }
}

// Wt2[p][k], p(np,g) = (np>>6)*256 + (g>>1)*128 + ((np>>4)&3)*32 + (g&1)*16 + (np&15)
// -> each wave's 4 N-fragments are the 4 gates of one 16-col np group.
__global__ void pack_w2_kernel(WPtrs p, __bf16* __restrict__ Wt) {
  __shared__ float tile[64][65];
  const int kt = blockIdx.x;  // 16 k-tiles of 64
  const int nt = blockIdx.y;  // 8 np-tiles of 64
  const int g = blockIdx.z;   // gate
  const int k0 = kt * 64, n0 = nt * 64;
  const float* src = (k0 < 512) ? p.wi[g] : p.wh[g];
  const int k0l = (k0 < 512) ? k0 : (k0 - 512);
  const int rr = threadIdx.x >> 6;
  const int cc = threadIdx.x & 63;
#pragma unroll
  for (int pp = 0; pp < 16; ++pp) {
    int kk = pp * 4 + rr;
    tile[kk][cc] = src[(size_t)(k0l + kk) * 512 + (n0 + cc)];
  }
  __syncthreads();
#pragma unroll
  for (int pp = 0; pp < 16; ++pp) {
    int nn = pp * 4 + rr;
    int np = n0 + nn;
    int prow = (np >> 6) * 256 + ((g >> 1) << 7) + (((np >> 4) & 3) << 5) +
               ((g & 1) << 4) + (np & 15);
    Wt[(size_t)prow * KDIM + (k0 + cc)] = (__bf16)tile[cc][nn];
  }
}

// ====================== v2 main: 256x256, BK=64, 8-phase ======================
__global__ __launch_bounds__(512, 1) void lstm_gemm2(
    const __bf16* __restrict__ Abf, const __bf16* __restrict__ Wt,
    const float* __restrict__ cin, const float* __restrict__ bias,
    float* __restrict__ out) {
  __shared__ alignas(16) char lds[131072];
  const int tid = threadIdx.x;
  const int wid = tid >> 6;
  const int wm = wid >> 2, wn = wid & 3;
  const int lane = tid & 63;
  const int fc = lane & 15, fg = lane >> 4;

  // XCD-aware swizzle (1024 % 8 == 0 -> simple bijection)
  const int wg = (blockIdx.x & 7) * 128 + (blockIdx.x >> 3);
  const int bm = wg >> 3, bn = wg & 7;

  const __bf16* Asrc = Abf + (size_t)bm * 256 * KDIM;
  const __bf16* Bsrc = Wt + (size_t)bn * 256 * KDIM;

  // staging geometry: one half-tile = [128 rows][64 k] bf16 = 16 KiB
  const int r0 = tid >> 3;                       // 0..63
  const int ssl = ((tid & 7) ^ (r0 & 7)) * 8;    // inverse-swizzled k-slot
  const uint32_t ldst0 = (uint32_t)(tid >> 6) * 1024;

  f32x4 acc[8][4];
#pragma unroll
  for (int m = 0; m < 8; ++m)
#pragma unroll
    for (int n = 0; n < 4; ++n) acc[m][n] = (f32x4){0.f, 0.f, 0.f, 0.f};

  bf16x8 a[4][2], b0[2][2], b1[2][2];

  auto stage = [&](const __bf16* base, int kt, uint32_t lbase) {
    const __bf16* g = base + (size_t)r0 * KDIM + kt * 64 + ssl;
    gll16(g, (void*)&lds[lbase + ldst0]);
    gll16(g + (size_t)64 * KDIM, (void*)&lds[lbase + 8192 + ldst0]);
  };
  auto stA = [&](int kt, int h) {
    if (kt < 16)
      stage(Asrc + (size_t)h * 128 * KDIM, kt,
            (uint32_t)(kt & 1) * 65536 + (uint32_t)h * 16384);
  };
  auto stB = [&](int kt, int h) {
    if (kt < 16)
      stage(Bsrc + (size_t)h * 128 * KDIM, kt,
            (uint32_t)(kt & 1) * 65536 + 32768 + (uint32_t)h * 16384);
  };
  auto ldA = [&](int cb, int h, int mq, int ks) -> bf16x8 {
    int row = wm * 64 + mq * 16 + fc;
    uint32_t off = (uint32_t)cb * 65536 + (uint32_t)h * 16384 +
                   (uint32_t)row * 128 +
                   (uint32_t)(((ks * 4 + fg) ^ (row & 7)) << 4);
    return *(const bf16x8*)&lds[off];
  };
  auto ldB = [&](int cb, int h, int nq, int ks) -> bf16x8 {
    int row = wn * 32 + nq * 16 + fc;
    uint32_t off = (uint32_t)cb * 65536 + 32768 + (uint32_t)h * 16384 +
                   (uint32_t)row * 128 +
                   (uint32_t)(((ks * 4 + fg) ^ (row & 7)) << 4);
    return *(const bf16x8*)&lds[off];
  };

  // prologue: 7 half-tiles in stream order [A0,B0,B1,A1] per tile
  stA(0, 0); stB(0, 0); stB(0, 1); stA(0, 1);
  stA(1, 0); stB(1, 0); stB(1, 1);
  asm volatile("s_waitcnt vmcnt(6)" ::: "memory");
  __builtin_amdgcn_s_barrier();

#pragma unroll 2
  for (int u = 0; u < 16; ++u) {
    const int cb = u & 1;
    // ---- P1: quad(A0,B0); stage A1(u+1) ----
#pragma unroll
    for (int mq = 0; mq < 4; ++mq)
#pragma unroll
      for (int ks = 0; ks < 2; ++ks) a[mq][ks] = ldA(cb, 0, mq, ks);
#pragma unroll
    for (int nq = 0; nq < 2; ++nq)
#pragma unroll
      for (int ks = 0; ks < 2; ++ks) b0[nq][ks] = ldB(cb, 0, nq, ks);
    stA(u + 1, 1);
    __builtin_amdgcn_s_barrier();
    asm volatile("s_waitcnt lgkmcnt(0)" ::: "memory");
    __builtin_amdgcn_s_setprio(1);
#pragma unroll
    for (int mq = 0; mq < 4; ++mq)
#pragma unroll
      for (int nq = 0; nq < 2; ++nq)
#pragma unroll
        for (int ks = 0; ks < 2; ++ks)
          MFMA16(a[mq][ks], b0[nq][ks], acc[mq][nq]);
    __builtin_amdgcn_s_setprio(0);
    __builtin_amdgcn_s_barrier();
    // ---- P2: quad(A0,B1); stage A0(u+2) ----
#pragma unroll
    for (int nq = 0; nq < 2; ++nq)
#pragma unroll
      for (int ks = 0; ks < 2; ++ks) b1[nq][ks] = ldB(cb, 1, nq, ks);
    stA(u + 2, 0);
    __builtin_amdgcn_s_barrier();
    asm volatile("s_waitcnt lgkmcnt(0)" ::: "memory");
    __builtin_amdgcn_s_setprio(1);
#pragma unroll
    for (int mq = 0; mq < 4; ++mq)
#pragma unroll
      for (int nq = 0; nq < 2; ++nq)
#pragma unroll
        for (int ks = 0; ks < 2; ++ks)
          MFMA16(a[mq][ks], b1[nq][ks], acc[mq][2 + nq]);
    __builtin_amdgcn_s_setprio(0);
    __builtin_amdgcn_s_barrier();
    // ---- P3: quad(A1,B1); stage B0(u+2) ----
#pragma unroll
    for (int mq = 0; mq < 4; ++mq)
#pragma unroll
      for (int ks = 0; ks < 2; ++ks) a[mq][ks] = ldA(cb, 1, mq, ks);
    stB(u + 2, 0);
    __builtin_amdgcn_s_barrier();
    asm volatile("s_waitcnt lgkmcnt(0)" ::: "memory");
    __builtin_amdgcn_s_setprio(1);
#pragma unroll
    for (int mq = 0; mq < 4; ++mq)
#pragma unroll
      for (int nq = 0; nq < 2; ++nq)
#pragma unroll
        for (int ks = 0; ks < 2; ++ks)
          MFMA16(a[mq][ks], b1[nq][ks], acc[4 + mq][2 + nq]);
    __builtin_amdgcn_s_setprio(0);
    __builtin_amdgcn_s_barrier();
    // ---- P4: quad(A1,B0); stage B1(u+2); counted vmcnt ----
    stB(u + 2, 1);
    if (u < 14) {
      asm volatile("s_waitcnt vmcnt(6)" ::: "memory");
    } else if (u == 14) {
      asm volatile("s_waitcnt vmcnt(0)" ::: "memory");
    }
    __builtin_amdgcn_s_barrier();
    __builtin_amdgcn_s_setprio(1);
#pragma unroll
    for (int mq = 0; mq < 4; ++mq)
#pragma unroll
      for (int nq = 0; nq < 2; ++nq)
#pragma unroll
        for (int ks = 0; ks < 2; ++ks)
          MFMA16(a[mq][ks], b0[nq][ks], acc[4 + mq][nq]);
    __builtin_amdgcn_s_setprio(0);
    __builtin_amdgcn_s_barrier();
  }

  // ---- fused LSTM epilogue (gates are acc[.][0..3] in-lane) ----
  const int np = bn * 64 + wn * 16 + fc;
  const float bi = bias[np];
  const float bf_ = bias[512 + np];
  const float bg = bias[1024 + np];
  const float bo = bias[1536 + np];
  const size_t couts = (size_t)NB * HDIM;
#pragma unroll
  for (int mf = 0; mf < 8; ++mf) {
    const int grow0 = bm * 256 + (mf >> 2) * 128 + wm * 64 + (mf & 3) * 16 + fg * 4;
#pragma unroll
    for (int j = 0; j < 4; ++j) {
      const size_t off = (size_t)(grow0 + j) * HDIM + np;
      float i_ = fsigmoid(acc[mf][0][j] + bi);
      float f_ = fsigmoid(acc[mf][1][j] + bf_);
      float g_ = fsigmoid(acc[mf][2][j] + bg);
      float o_ = fsigmoid(acc[mf][3][j] + bo);
      float cp = f_ * cin[off] + i_ * g_;
      out[off] = o_ * ftanh(cp);
      out[couts + off] = cp;
    }
  }
}

// ====================== v1 fallback (round-1, proven) ======================
__global__ void pack_w1_kernel(WPtrs p, __bf16* __restrict__ Wt) {
  __shared__ float tile[64][65];
  const int kt = blockIdx.x;
  const int nt = blockIdx.y;
  const int g = blockIdx.z;
  const int k0 = kt * 64, n0 = nt * 64;
  const float* src = (k0 < 512) ? p.wi[g] : p.wh[g];
  const int k0l = (k0 < 512) ? k0 : (k0 - 512);
  const int rr = threadIdx.x >> 6;
  const int cc = threadIdx.x & 63;
#pragma unroll
  for (int pp = 0; pp < 16; ++pp) {
    int kk = pp * 4 + rr;
    tile[kk][cc] = src[(size_t)(k0l + kk) * 512 + (n0 + cc)];
  }
  __syncthreads();
#pragma unroll
  for (int pp = 0; pp < 16; ++pp) {
    int nn = pp * 4 + rr;
    int np = n0 + nn;
    int prow = ((np >> 5) << 7) + g * 32 + (np & 31);
    Wt[(size_t)prow * KDIM + (k0 + cc)] = (__bf16)tile[cc][nn];
  }
}

__global__ __launch_bounds__(256) void lstm_gemm1(
    const float* __restrict__ xin, const float* __restrict__ hin,
    const float* __restrict__ cin, const __bf16* __restrict__ Wt,
    const float* __restrict__ bias, float* __restrict__ out) {
  __shared__ alignas(16) __bf16 Alds[2][128 * 32];
  __shared__ alignas(16) __bf16 Blds[2][128 * 32];
  const int tid = threadIdx.x;
  const int w = tid >> 6;
  const int lane = tid & 63;
  const int bid = blockIdx.x;
  const int bm = bid >> 4;
  const int bn = bid & 15;
  f32x4 acc[2][8];
#pragma unroll
  for (int m = 0; m < 2; ++m)
#pragma unroll
    for (int n = 0; n < 8; ++n) acc[m][n] = (f32x4){0.f, 0.f, 0.f, 0.f};
  const int ra = tid >> 2;
  const int q = tid & 3;
  const size_t arow0 = (size_t)(bm * 128 + ra) * 512;
  const size_t arow1 = (size_t)(bm * 128 + ra + 64) * 512;
  const int fc = lane & 15;
  const int fg = lane >> 4;
  const int kg8 = fg * 8;
  {
    const int k = q * 8;
    float4 v0 = *(const float4*)(xin + arow0 + k);
    float4 v1 = *(const float4*)(xin + arow0 + k + 4);
    float4 v2 = *(const float4*)(xin + arow1 + k);
    float4 v3 = *(const float4*)(xin + arow1 + k + 4);
    *(bf16x8*)&Alds[0][ra * 32 + q * 8] = pack8(v0, v1);
    *(bf16x8*)&Alds[0][(ra + 64) * 32 + q * 8] = pack8(v2, v3);
    const __bf16* bs0 = Wt + (size_t)(bn * 128 + ra) * KDIM + q * 8;
    gll16(bs0, (void*)&Blds[0][w * 512]);
    gll16(bs0 + (size_t)64 * KDIM, (void*)&Blds[0][2048 + w * 512]);
  }
  __syncthreads();
#pragma unroll 2
  for (int kt = 0; kt < 32; ++kt) {
    const int cur = kt & 1;
    const int nxt = cur ^ 1;
    float4 v0, v1, v2, v3;
    const bool pf = (kt < 31);
    if (pf) {
      const int kg = (kt + 1) * 32 + q * 8;
      const float* srcb = (kg < 512) ? (xin + kg) : (hin + (kg - 512));
      v0 = *(const float4*)(srcb + arow0);
      v1 = *(const float4*)(srcb + arow0 + 4);
      v2 = *(const float4*)(srcb + arow1);
      v3 = *(const float4*)(srcb + arow1 + 4);
      const __bf16* bs0 =
          Wt + (size_t)(bn * 128 + ra) * KDIM + (kt + 1) * 32 + q * 8;
      gll16(bs0, (void*)&Blds[nxt][w * 512]);
      gll16(bs0 + (size_t)64 * KDIM, (void*)&Blds[nxt][2048 + w * 512]);
    }
    bf16x8 af0 = *(const bf16x8*)&Alds[cur][(w * 32 + fc) * 32 + kg8];
    bf16x8 af1 = *(const bf16x8*)&Alds[cur][(w * 32 + 16 + fc) * 32 + kg8];
#pragma unroll
    for (int nf = 0; nf < 8; ++nf) {
      bf16x8 bfrag = *(const bf16x8*)&Blds[cur][(nf * 16 + fc) * 32 + kg8];
      MFMA16(af0, bfrag, acc[0][nf]);
      MFMA16(af1, bfrag, acc[1][nf]);
    }
    if (pf) {
      *(bf16x8*)&Alds[nxt][ra * 32 + q * 8] = pack8(v0, v1);
      *(bf16x8*)&Alds[nxt][(ra + 64) * 32 + q * 8] = pack8(v2, v3);
    }
    __syncthreads();
  }
  const size_t couts = (size_t)NB * HDIM;
#pragma unroll
  for (int nn = 0; nn < 2; ++nn) {
    const int np = bn * 32 + nn * 16 + fc;
    const float bi = bias[np];
    const float bff = bias[512 + np];
    const float bg = bias[1024 + np];
    const float bo = bias[1536 + np];
#pragma unroll
    for (int m = 0; m < 2; ++m) {
      const int rbase = bm * 128 + w * 32 + m * 16 + fg * 4;
#pragma unroll
      for (int j = 0; j < 4; ++j) {
        const size_t off = (size_t)(rbase + j) * HDIM + np;
        float i_ = fsigmoid(acc[m][nn][j] + bi);
        float f_ = fsigmoid(acc[m][2 + nn][j] + bff);
        float g_ = fsigmoid(acc[m][4 + nn][j] + bg);
        float o_ = fsigmoid(acc[m][6 + nn][j] + bo);
        float cp = f_ * cin[off] + i_ * g_;
        float hp = o_ * ftanh(cp);
        out[off] = hp;
        out[couts + off] = cp;
      }
    }
  }
}

// ====================== launch ======================
extern "C" void kernel_launch(void* const* d_in, const int* in_sizes, int n_in,
                              void* d_out, int out_size, void* d_ws,
                              size_t ws_size, hipStream_t stream) {
  const float* xin = (const float*)d_in[0];
  const float* hin = (const float*)d_in[1];
  const float* cin = (const float*)d_in[2];
  WPtrs wp;
  wp.wi[0] = (const float*)d_in[3];
  wp.wi[1] = (const float*)d_in[7];
  wp.wi[2] = (const float*)d_in[11];
  wp.wi[3] = (const float*)d_in[15];
  wp.wh[0] = (const float*)d_in[4];
  wp.wh[1] = (const float*)d_in[8];
  wp.wh[2] = (const float*)d_in[12];
  wp.wh[3] = (const float*)d_in[16];
  BPtrs bp;
  bp.bi[0] = (const float*)d_in[5];
  bp.bi[1] = (const float*)d_in[9];
  bp.bi[2] = (const float*)d_in[13];
  bp.bi[3] = (const float*)d_in[17];
  bp.bh[0] = (const float*)d_in[6];
  bp.bh[1] = (const float*)d_in[10];
  bp.bh[2] = (const float*)d_in[14];
  bp.bh[3] = (const float*)d_in[18];

  const size_t needA = (size_t)NB * KDIM * 2;      // 64 MiB
  const size_t needW = (size_t)2048 * KDIM * 2;    // 4 MiB
  const size_t needBias = (size_t)4 * HDIM * 4;    // 8 KiB

  if (ws_size >= needA + needW + needBias) {
    __bf16* Abf = (__bf16*)d_ws;
    __bf16* Wt = (__bf16*)((char*)d_ws + needA);
    float* bias = (float*)((char*)d_ws + needA + needW);
    conv_a_kernel<<<2048, 256, 0, stream>>>(xin, hin, Abf);
    pack_w2_kernel<<<dim3(16, 8, 4), 256, 0, stream>>>(wp, Wt);
    pack_bias_kernel<<<8, 256, 0, stream>>>(bp, bias);
    lstm_gemm2<<<1024, 512, 0, stream>>>(Abf, Wt, cin, bias, (float*)d_out);
  } else {
    __bf16* Wt = (__bf16*)d_ws;
    float* bias = (float*)((char*)d_ws + needW);
    pack_w1_kernel<<<dim3(16, 8, 4), 256, 0, stream>>>(wp, Wt);
    pack_bias_kernel<<<8, 256, 0, stream>>>(bp, bias);
    lstm_gemm1<<<4096, 256, 0, stream>>>(xin, hin, cin, Wt, bias,
                                         (float*)d_out);
  }
}

// Round 3
// 213.834 us; speedup vs baseline: 1.7012x; 1.0018x over previous
//
#include <hip/hip_runtime.h>
#include <hip/hip_bf16.h>

typedef __attribute__((ext_vector_type(8))) __bf16 bf16x8;
typedef __attribute__((ext_vector_type(4))) float f32x4;

#define NB 32768
#define HDIM 512
#define KDIM 1024

struct WPtrs { const float* wi[4]; const float* wh[4]; };
struct BPtrs { const float* bi[4]; const float* bh[4]; };

__device__ __forceinline__ float fsigmoid(float x) {
  return 1.0f / (1.0f + __expf(-x));
}
__device__ __forceinline__ float ftanh(float x) {
  return 2.0f / (1.0f + __expf(-2.0f * x)) - 1.0f;
}
__device__ __forceinline__ bf16x8 pack8(float4 a, float4 b) {
  bf16x8 r;
  r[0] = (__bf16)a.x; r[1] = (__bf16)a.y; r[2] = (__bf16)a.z; r[3] = (__bf16)a.w;
  r[4] = (__bf16)b.x; r[5] = (__bf16)b.y; r[6] = (__bf16)b.z; r[7] = (__bf16)b.w;
  return r;
}
__device__ __forceinline__ void gll16(const void* g, void* l) {
  __builtin_amdgcn_global_load_lds(
      (const __attribute__((address_space(1))) void*)g,
      (__attribute__((address_space(3))) void*)l, 16, 0, 0);
}
#define MFMA16(A, B, C) \
  C = __builtin_amdgcn_mfma_f32_16x16x32_bf16(A, B, C, 0, 0, 0)

// ====================== prep ======================
__global__ void pack_bias_kernel(BPtrs p, float* __restrict__ bias) {
  int idx = blockIdx.x * 256 + threadIdx.x;  // 0..2047
  int g = idx >> 9, np = idx & 511;
  bias[idx] = p.bi[g][np] + p.bh[g][np];
}

// A = [x | h] -> bf16 [32768][1024]
__global__ void conv_a_kernel(const float* __restrict__ x,
                              const float* __restrict__ h,
                              __bf16* __restrict__ Abf) {
  const size_t N8 = (size_t)NB * KDIM / 8;
  for (size_t i = (size_t)blockIdx.x * blockDim.x + threadIdx.x; i < N8;
       i += (size_t)gridDim.x * blockDim.x) {
    size_t e = i * 8;
    int k = (int)(e & (KDIM - 1));
    size_t r = e >> 10;
    const float* s = (k < 512) ? (x + r * 512 + k) : (h + r * 512 + (k - 512));
    float4 v0 = *(const float4*)s;
    float4 v1 = *(const float4*)(s + 4);
    *(bf16x8*)(Abf + e) = pack8(v0, v1);
  }
}

// Wt[p][k], p(np,g) = (np>>6)*256 + (g>>1)*128 + ((np>>4)&3)*32 + (g&1)*16 + (np&15)
__global__ void pack_w2_kernel(WPtrs p, __bf16* __restrict__ Wt) {
  __shared__ float tile[64][65];
  const int kt = blockIdx.x;  // 16 k-tiles of 64
  const int nt = blockIdx.y;  // 8 np-tiles of 64
  const int g = blockIdx.z;   // gate
  const int k0 = kt * 64, n0 = nt * 64;
  const float* src = (k0 < 512) ? p.wi[g] : p.wh[g];
  const int k0l = (k0 < 512) ? k0 : (k0 - 512);
  const int rr = threadIdx.x >> 6;
  const int cc = threadIdx.x & 63;
#pragma unroll
  for (int pp = 0; pp < 16; ++pp) {
    int kk = pp * 4 + rr;
    tile[kk][cc] = src[(size_t)(k0l + kk) * 512 + (n0 + cc)];
  }
  __syncthreads();
#pragma unroll
  for (int pp = 0; pp < 16; ++pp) {
    int nn = pp * 4 + rr;
    int np = n0 + nn;
    int prow = (np >> 6) * 256 + ((g >> 1) << 7) + (((np >> 4) & 3) << 5) +
               ((g & 1) << 4) + (np & 15);
    Wt[(size_t)prow * KDIM + (k0 + cc)] = (__bf16)tile[cc][nn];
  }
}

// ====================== persistent main: 256 blocks, 4 bm-groups each ======================
__global__ __launch_bounds__(512, 1) void lstm_gemm3(
    const __bf16* __restrict__ Abf, const __bf16* __restrict__ Wt,
    const float* __restrict__ cin, const float* __restrict__ bias,
    float* __restrict__ out) {
  __shared__ alignas(16) char lds[131072];
  const int tid = threadIdx.x;
  const int wid = tid >> 6;
  const int wm = wid >> 2, wn = wid & 3;
  const int lane = tid & 63;
  const int fc = lane & 15, fg = lane >> 4;

  // one bn-panel per XCD (bid%8 ~ XCD); 32 bm-groups spread over its 32 CUs
  const int bn = blockIdx.x & 7;
  const int bmg = blockIdx.x >> 3;  // 0..31, each covers 4 x 256 rows

  const __bf16* Bsrc = Wt + (size_t)bn * 256 * KDIM;

  // staging geometry: half-tile = [128 rows][64 k] bf16 = 16 KiB, linear LDS,
  // inverse-swizzled global k-slot (rule #21: swizzle source + read, linear dest)
  const int r0 = tid >> 3;                     // 0..63
  const int ssl = ((tid & 7) ^ (r0 & 7)) * 8;  // global k-slot (8 bf16 = 16B)
  const uint32_t ldst0 = (uint32_t)(tid >> 6) * 1024;

  f32x4 acc[8][4];
#pragma unroll
  for (int m = 0; m < 8; ++m)
#pragma unroll
    for (int n = 0; n < 4; ++n) acc[m][n] = (f32x4){0.f, 0.f, 0.f, 0.f};

  bf16x8 a[4][2], b0[2][2], b1[2][2];

  auto stA = [&](int t, int h) {
    if (t < 64) {
      const __bf16* g = Abf +
                        ((size_t)((bmg << 2) + (t >> 4)) * 256 + h * 128 + r0) *
                            KDIM +
                        (t & 15) * 64 + ssl;
      uint32_t lb = (uint32_t)(t & 1) * 65536 + (uint32_t)h * 16384 + ldst0;
      gll16(g, (void*)&lds[lb]);
      gll16(g + (size_t)64 * KDIM, (void*)&lds[lb + 8192]);
    }
  };
  auto stB = [&](int t, int h) {
    if (t < 64) {
      const __bf16* g =
          Bsrc + ((size_t)h * 128 + r0) * KDIM + (t & 15) * 64 + ssl;
      uint32_t lb =
          (uint32_t)(t & 1) * 65536 + 32768 + (uint32_t)h * 16384 + ldst0;
      gll16(g, (void*)&lds[lb]);
      gll16(g + (size_t)64 * KDIM, (void*)&lds[lb + 8192]);
    }
  };
  auto ldA = [&](int cb, int h, int mq, int ks) -> bf16x8 {
    int row = wm * 64 + mq * 16 + fc;
    uint32_t off = (uint32_t)cb * 65536 + (uint32_t)h * 16384 +
                   (uint32_t)row * 128 +
                   (uint32_t)(((ks * 4 + fg) ^ (row & 7)) << 4);
    return *(const bf16x8*)&lds[off];
  };
  auto ldB = [&](int cb, int h, int nq, int ks) -> bf16x8 {
    int row = wn * 32 + nq * 16 + fc;
    uint32_t off = (uint32_t)cb * 65536 + 32768 + (uint32_t)h * 16384 +
                   (uint32_t)row * 128 +
                   (uint32_t)(((ks * 4 + fg) ^ (row & 7)) << 4);
    return *(const bf16x8*)&lds[off];
  };

  // hoisted epilogue constants (np fixed per thread across all groups)
  const int np = bn * 64 + wn * 16 + fc;
  const float bi = bias[np];
  const float bf_ = bias[512 + np];
  const float bg = bias[1024 + np];
  const float bo = bias[1536 + np];
  const size_t couts = (size_t)NB * HDIM;

  // prologue: 7 half-tiles, stream order [A0,B0,B1,A1] per tile
  stA(0, 0); stB(0, 0); stB(0, 1); stA(0, 1);
  stA(1, 0); stB(1, 0); stB(1, 1);
  asm volatile("s_waitcnt vmcnt(6)" ::: "memory");
  __builtin_amdgcn_s_barrier();

#pragma unroll 2
  for (int t = 0; t < 64; ++t) {
    const int cb = t & 1;
    // ---- P1: quad(A0,B0); stage A1(t+1) ----
#pragma unroll
    for (int mq = 0; mq < 4; ++mq)
#pragma unroll
      for (int ks = 0; ks < 2; ++ks) a[mq][ks] = ldA(cb, 0, mq, ks);
#pragma unroll
    for (int nq = 0; nq < 2; ++nq)
#pragma unroll
      for (int ks = 0; ks < 2; ++ks) b0[nq][ks] = ldB(cb, 0, nq, ks);
    stA(t + 1, 1);
    __builtin_amdgcn_s_barrier();
    asm volatile("s_waitcnt lgkmcnt(0)" ::: "memory");
    __builtin_amdgcn_s_setprio(1);
#pragma unroll
    for (int mq = 0; mq < 4; ++mq)
#pragma unroll
      for (int nq = 0; nq < 2; ++nq)
#pragma unroll
        for (int ks = 0; ks < 2; ++ks)
          MFMA16(a[mq][ks], b0[nq][ks], acc[mq][nq]);
    __builtin_amdgcn_s_setprio(0);
    __builtin_amdgcn_s_barrier();
    // ---- P2: quad(A0,B1); stage A0(t+2) ----
#pragma unroll
    for (int nq = 0; nq < 2; ++nq)
#pragma unroll
      for (int ks = 0; ks < 2; ++ks) b1[nq][ks] = ldB(cb, 1, nq, ks);
    stA(t + 2, 0);
    __builtin_amdgcn_s_barrier();
    asm volatile("s_waitcnt lgkmcnt(0)" ::: "memory");
    __builtin_amdgcn_s_setprio(1);
#pragma unroll
    for (int mq = 0; mq < 4; ++mq)
#pragma unroll
      for (int nq = 0; nq < 2; ++nq)
#pragma unroll
        for (int ks = 0; ks < 2; ++ks)
          MFMA16(a[mq][ks], b1[nq][ks], acc[mq][2 + nq]);
    __builtin_amdgcn_s_setprio(0);
    __builtin_amdgcn_s_barrier();
    // ---- P3: quad(A1,B1); stage B0(t+2) ----
#pragma unroll
    for (int mq = 0; mq < 4; ++mq)
#pragma unroll
      for (int ks = 0; ks < 2; ++ks) a[mq][ks] = ldA(cb, 1, mq, ks);
    stB(t + 2, 0);
    __builtin_amdgcn_s_barrier();
    asm volatile("s_waitcnt lgkmcnt(0)" ::: "memory");
    __builtin_amdgcn_s_setprio(1);
#pragma unroll
    for (int mq = 0; mq < 4; ++mq)
#pragma unroll
      for (int nq = 0; nq < 2; ++nq)
#pragma unroll
        for (int ks = 0; ks < 2; ++ks)
          MFMA16(a[mq][ks], b1[nq][ks], acc[4 + mq][2 + nq]);
    __builtin_amdgcn_s_setprio(0);
    __builtin_amdgcn_s_barrier();
    // ---- P4: quad(A1,B0); stage B1(t+2); counted vmcnt ----
    stB(t + 2, 1);
    if (t < 62) {
      asm volatile("s_waitcnt vmcnt(6)" ::: "memory");
    } else if (t == 62) {
      asm volatile("s_waitcnt vmcnt(0)" ::: "memory");
    }
    __builtin_amdgcn_s_barrier();
    __builtin_amdgcn_s_setprio(1);
#pragma unroll
    for (int mq = 0; mq < 4; ++mq)
#pragma unroll
      for (int nq = 0; nq < 2; ++nq)
#pragma unroll
        for (int ks = 0; ks < 2; ++ks)
          MFMA16(a[mq][ks], b0[nq][ks], acc[4 + mq][nq]);
    __builtin_amdgcn_s_setprio(0);
    __builtin_amdgcn_s_barrier();

    // ---- inline LSTM epilogue at group end (regs+global only; no LDS, no
    // barrier: tiles t+1,t+2 already staged/in flight, pipeline keeps running)
    if ((t & 15) == 15) {
      const int g = t >> 4;
#pragma unroll
      for (int mf = 0; mf < 8; ++mf) {
        const int grow0 = ((bmg << 2) + g) * 256 + (mf >> 2) * 128 + wm * 64 +
                          (mf & 3) * 16 + fg * 4;
#pragma unroll
        for (int j = 0; j < 4; ++j) {
          const size_t off = (size_t)(grow0 + j) * HDIM + np;
          float i_ = fsigmoid(acc[mf][0][j] + bi);
          float f_ = fsigmoid(acc[mf][1][j] + bf_);
          float g_ = fsigmoid(acc[mf][2][j] + bg);
          float o_ = fsigmoid(acc[mf][3][j] + bo);
          float cp = f_ * cin[off] + i_ * g_;
          out[off] = o_ * ftanh(cp);
          out[couts + off] = cp;
        }
#pragma unroll
        for (int n = 0; n < 4; ++n) acc[mf][n] = (f32x4){0.f, 0.f, 0.f, 0.f};
      }
    }
  }
}

// ====================== launch ======================
extern "C" void kernel_launch(void* const* d_in, const int* in_sizes, int n_in,
                              void* d_out, int out_size, void* d_ws,
                              size_t ws_size, hipStream_t stream) {
  const float* xin = (const float*)d_in[0];
  const float* hin = (const float*)d_in[1];
  const float* cin = (const float*)d_in[2];
  WPtrs wp;
  wp.wi[0] = (const float*)d_in[3];
  wp.wi[1] = (const float*)d_in[7];
  wp.wi[2] = (const float*)d_in[11];
  wp.wi[3] = (const float*)d_in[15];
  wp.wh[0] = (const float*)d_in[4];
  wp.wh[1] = (const float*)d_in[8];
  wp.wh[2] = (const float*)d_in[12];
  wp.wh[3] = (const float*)d_in[16];
  BPtrs bp;
  bp.bi[0] = (const float*)d_in[5];
  bp.bi[1] = (const float*)d_in[9];
  bp.bi[2] = (const float*)d_in[13];
  bp.bi[3] = (const float*)d_in[17];
  bp.bh[0] = (const float*)d_in[6];
  bp.bh[1] = (const float*)d_in[10];
  bp.bh[2] = (const float*)d_in[14];
  bp.bh[3] = (const float*)d_in[18];

  const size_t needA = (size_t)NB * KDIM * 2;    // 64 MiB
  const size_t needW = (size_t)2048 * KDIM * 2;  // 4 MiB

  __bf16* Abf = (__bf16*)d_ws;
  __bf16* Wt = (__bf16*)((char*)d_ws + needA);
  float* bias = (float*)((char*)d_ws + needA + needW);

  conv_a_kernel<<<2048, 256, 0, stream>>>(xin, hin, Abf);
  pack_w2_kernel<<<dim3(16, 8, 4), 256, 0, stream>>>(wp, Wt);
  pack_bias_kernel<<<8, 256, 0, stream>>>(bp, bias);
  lstm_gemm3<<<256, 512, 0, stream>>>(Abf, Wt, cin, bias, (float*)d_out);
}

// Round 4
// 210.673 us; speedup vs baseline: 1.7267x; 1.0150x over previous
//
#include <hip/hip_runtime.h>
#include <hip/hip_bf16.h>

typedef __attribute__((ext_vector_type(8))) __bf16 bf16x8;
typedef __attribute__((ext_vector_type(4))) float f32x4;

#define NB 32768
#define HDIM 512
#define KDIM 1024

struct WPtrs { const float* wi[4]; const float* wh[4]; };
struct BPtrs { const float* bi[4]; const float* bh[4]; };

__device__ __forceinline__ float fsigmoid(float x) {
  return 1.0f / (1.0f + __expf(-x));
}
__device__ __forceinline__ float ftanh(float x) {
  return 2.0f / (1.0f + __expf(-2.0f * x)) - 1.0f;
}
__device__ __forceinline__ bf16x8 pack8(float4 a, float4 b) {
  bf16x8 r;
  r[0] = (__bf16)a.x; r[1] = (__bf16)a.y; r[2] = (__bf16)a.z; r[3] = (__bf16)a.w;
  r[4] = (__bf16)b.x; r[5] = (__bf16)b.y; r[6] = (__bf16)b.z; r[7] = (__bf16)b.w;
  return r;
}
__device__ __forceinline__ void gll16(const void* g, void* l) {
  __builtin_amdgcn_global_load_lds(
      (const __attribute__((address_space(1))) void*)g,
      (__attribute__((address_space(3))) void*)l, 16, 0, 0);
}
#define MFMA16(A, B, C) \
  C = __builtin_amdgcn_mfma_f32_16x16x32_bf16(A, B, C, 0, 0, 0)
#define SBAR() __builtin_amdgcn_s_barrier()
#define SCHED0() __builtin_amdgcn_sched_barrier(0)

// ====================== prep ======================
__global__ void pack_bias_kernel(BPtrs p, float* __restrict__ bias) {
  int idx = blockIdx.x * 256 + threadIdx.x;  // 0..2047
  int g = idx >> 9, np = idx & 511;
  bias[idx] = p.bi[g][np] + p.bh[g][np];
}

// A = [x | h] -> bf16 [32768][1024]
__global__ void conv_a_kernel(const float* __restrict__ x,
                              const float* __restrict__ h,
                              __bf16* __restrict__ Abf) {
  const size_t N8 = (size_t)NB * KDIM / 8;
  for (size_t i = (size_t)blockIdx.x * blockDim.x + threadIdx.x; i < N8;
       i += (size_t)gridDim.x * blockDim.x) {
    size_t e = i * 8;
    int k = (int)(e & (KDIM - 1));
    size_t r = e >> 10;
    const float* s = (k < 512) ? (x + r * 512 + k) : (h + r * 512 + (k - 512));
    float4 v0 = *(const float4*)s;
    float4 v1 = *(const float4*)(s + 4);
    *(bf16x8*)(Abf + e) = pack8(v0, v1);
  }
}

// Wt[p][k], p(np,g) = (np>>6)*256 + (g>>1)*128 + ((np>>4)&3)*32 + (g&1)*16 + (np&15)
__global__ void pack_w2_kernel(WPtrs p, __bf16* __restrict__ Wt) {
  __shared__ float tile[64][65];
  const int kt = blockIdx.x;  // 16 k-tiles of 64
  const int nt = blockIdx.y;  // 8 np-tiles of 64
  const int g = blockIdx.z;   // gate
  const int k0 = kt * 64, n0 = nt * 64;
  const float* src = (k0 < 512) ? p.wi[g] : p.wh[g];
  const int k0l = (k0 < 512) ? k0 : (k0 - 512);
  const int rr = threadIdx.x >> 6;
  const int cc = threadIdx.x & 63;
#pragma unroll
  for (int pp = 0; pp < 16; ++pp) {
    int kk = pp * 4 + rr;
    tile[kk][cc] = src[(size_t)(k0l + kk) * 512 + (n0 + cc)];
  }
  __syncthreads();
#pragma unroll
  for (int pp = 0; pp < 16; ++pp) {
    int nn = pp * 4 + rr;
    int np = n0 + nn;
    int prow = (np >> 6) * 256 + ((g >> 1) << 7) + (((np >> 4) & 3) << 5) +
               ((g & 1) << 4) + (np & 15);
    Wt[(size_t)prow * KDIM + (k0 + cc)] = (__bf16)tile[cc][nn];
  }
}

// ====================== persistent main, counted-lgkm pipeline ======================
// Hazard audit (LDS regions of buffer cb, per K-tile t):
//   A-h0 read P1 (done by lgkm<=4 pre-P1bar) ; re-staged P2 (post-P1bar)  OK
//   B-h0 read P1 (done by lgkm<=4 pre-P1bar) ; re-staged P3 (post-P1bar)  OK
//   B-h1 read P1, consumed P2 (lgkm0 pre-P2bar); re-staged P4 (post-P2bar) OK
//   A-h1 read end-P2/P3 (done by lgkm0 pre-P3bar); re-staged P1(t+2) (post-P3bar) OK
//   tile t+1 residency: vmcnt(6)@P4(t) completes all 4 half-tiles of t+1, + barrier.
__global__ __launch_bounds__(512, 1) void lstm_gemm4(
    const __bf16* __restrict__ Abf, const __bf16* __restrict__ Wt,
    const float* __restrict__ cin, const float* __restrict__ bias,
    float* __restrict__ out) {
  __shared__ alignas(16) char lds[131072];
  const int tid = threadIdx.x;
  const int wid = tid >> 6;
  const int wm = wid >> 2, wn = wid & 3;
  const int lane = tid & 63;
  const int fc = lane & 15, fg = lane >> 4;

  const int bn = blockIdx.x & 7;
  const int bmg = blockIdx.x >> 3;  // 0..31, each covers 4 x 256 rows

  const __bf16* Bsrc = Wt + (size_t)bn * 256 * KDIM;

  const int r0 = tid >> 3;                     // 0..63
  const int ssl = ((tid & 7) ^ (r0 & 7)) * 8;  // inverse-swizzled k-slot
  const uint32_t ldst0 = (uint32_t)(tid >> 6) * 1024;

  f32x4 acc[8][4];
#pragma unroll
  for (int m = 0; m < 8; ++m)
#pragma unroll
    for (int n = 0; n < 4; ++n) acc[m][n] = (f32x4){0.f, 0.f, 0.f, 0.f};

  bf16x8 a[4][2], b0[2][2], b1[2][2];

  auto stA = [&](int t, int h) {
    if (t < 64) {
      const __bf16* g = Abf +
                        ((size_t)((bmg << 2) + (t >> 4)) * 256 + h * 128 + r0) *
                            KDIM +
                        (t & 15) * 64 + ssl;
      uint32_t lb = (uint32_t)(t & 1) * 65536 + (uint32_t)h * 16384 + ldst0;
      gll16(g, (void*)&lds[lb]);
      gll16(g + (size_t)64 * KDIM, (void*)&lds[lb + 8192]);
    }
  };
  auto stB = [&](int t, int h) {
    if (t < 64) {
      const __bf16* g =
          Bsrc + ((size_t)h * 128 + r0) * KDIM + (t & 15) * 64 + ssl;
      uint32_t lb =
          (uint32_t)(t & 1) * 65536 + 32768 + (uint32_t)h * 16384 + ldst0;
      gll16(g, (void*)&lds[lb]);
      gll16(g + (size_t)64 * KDIM, (void*)&lds[lb + 8192]);
    }
  };
  auto ldA = [&](int cb, int h, int mq, int ks) -> bf16x8 {
    int row = wm * 64 + mq * 16 + fc;
    uint32_t off = (uint32_t)cb * 65536 + (uint32_t)h * 16384 +
                   (uint32_t)row * 128 +
                   (uint32_t)(((ks * 4 + fg) ^ (row & 7)) << 4);
    return *(const bf16x8*)&lds[off];
  };
  auto ldB = [&](int cb, int h, int nq, int ks) -> bf16x8 {
    int row = wn * 32 + nq * 16 + fc;
    uint32_t off = (uint32_t)cb * 65536 + 32768 + (uint32_t)h * 16384 +
                   (uint32_t)row * 128 +
                   (uint32_t)(((ks * 4 + fg) ^ (row & 7)) << 4);
    return *(const bf16x8*)&lds[off];
  };

  // hoisted epilogue constants
  const int np = bn * 64 + wn * 16 + fc;
  const float bi = bias[np];
  const float bf_ = bias[512 + np];
  const float bg = bias[1024 + np];
  const float bo = bias[1536 + np];
  const size_t couts = (size_t)NB * HDIM;

  // prologue: 7 half-tiles [A0,B0,B1,A1 | A0,B0,B1]
  stA(0, 0); stB(0, 0); stB(0, 1); stA(0, 1);
  stA(1, 0); stB(1, 0); stB(1, 1);
  asm volatile("s_waitcnt vmcnt(6)" ::: "memory");
  SBAR();

#pragma unroll 2
  for (int t = 0; t < 64; ++t) {
    const int cb = t & 1;
    // ================= P1: MFMA(ah0,b0); stage A(t+1,h1) =================
    // upfront reads, issue order: b0(4), a-h0(8), b1(4)
#pragma unroll
    for (int nq = 0; nq < 2; ++nq)
#pragma unroll
      for (int ks = 0; ks < 2; ++ks) b0[nq][ks] = ldB(cb, 0, nq, ks);
#pragma unroll
    for (int mq = 0; mq < 4; ++mq)
#pragma unroll
      for (int ks = 0; ks < 2; ++ks) a[mq][ks] = ldA(cb, 0, mq, ks);
#pragma unroll
    for (int nq = 0; nq < 2; ++nq)
#pragma unroll
      for (int ks = 0; ks < 2; ++ks) b1[nq][ks] = ldB(cb, 1, nq, ks);
    stA(t + 1, 1);
    asm volatile("s_waitcnt lgkmcnt(8)" ::: "memory");  // b0 + a[0..1] ready
    SCHED0();
    __builtin_amdgcn_s_setprio(1);
#pragma unroll
    for (int mq = 0; mq < 2; ++mq)
#pragma unroll
      for (int nq = 0; nq < 2; ++nq)
#pragma unroll
        for (int ks = 0; ks < 2; ++ks)
          MFMA16(a[mq][ks], b0[nq][ks], acc[mq][nq]);
    __builtin_amdgcn_s_setprio(0);
    asm volatile("s_waitcnt lgkmcnt(4)" ::: "memory");  // a[2..3] ready
    SCHED0();
    __builtin_amdgcn_s_setprio(1);
#pragma unroll
    for (int mq = 2; mq < 4; ++mq)
#pragma unroll
      for (int nq = 0; nq < 2; ++nq)
#pragma unroll
        for (int ks = 0; ks < 2; ++ks)
          MFMA16(a[mq][ks], b0[nq][ks], acc[mq][nq]);
    __builtin_amdgcn_s_setprio(0);
    SBAR();
    // ================= P2: MFMA(ah0,b1); stage A(t+2,h0); reload a<-h1 ====
    stA(t + 2, 0);
    asm volatile("s_waitcnt lgkmcnt(0)" ::: "memory");  // b1 (drained under P1)
    SCHED0();
    __builtin_amdgcn_s_setprio(1);
#pragma unroll
    for (int mq = 0; mq < 4; ++mq)
#pragma unroll
      for (int nq = 0; nq < 2; ++nq)
#pragma unroll
        for (int ks = 0; ks < 2; ++ks)
          MFMA16(a[mq][ks], b1[nq][ks], acc[mq][2 + nq]);
    __builtin_amdgcn_s_setprio(0);
    // a-regs dead (as ah0) -> reload as ah1; drains under barrier + P3 stage
#pragma unroll
    for (int mq = 0; mq < 4; ++mq)
#pragma unroll
      for (int ks = 0; ks < 2; ++ks) a[mq][ks] = ldA(cb, 1, mq, ks);
    SCHED0();
    SBAR();
    // ================= P3: MFMA(ah1,b1); stage B(t+2,h0) =================
    stB(t + 2, 0);
    asm volatile("s_waitcnt lgkmcnt(4)" ::: "memory");  // a[0..1] ready
    SCHED0();
    __builtin_amdgcn_s_setprio(1);
#pragma unroll
    for (int mq = 0; mq < 2; ++mq)
#pragma unroll
      for (int nq = 0; nq < 2; ++nq)
#pragma unroll
        for (int ks = 0; ks < 2; ++ks)
          MFMA16(a[mq][ks], b1[nq][ks], acc[4 + mq][2 + nq]);
    __builtin_amdgcn_s_setprio(0);
    asm volatile("s_waitcnt lgkmcnt(0)" ::: "memory");  // a[2..3] ready
    SCHED0();
    __builtin_amdgcn_s_setprio(1);
#pragma unroll
    for (int mq = 2; mq < 4; ++mq)
#pragma unroll
      for (int nq = 0; nq < 2; ++nq)
#pragma unroll
        for (int ks = 0; ks < 2; ++ks)
          MFMA16(a[mq][ks], b1[nq][ks], acc[4 + mq][2 + nq]);
    __builtin_amdgcn_s_setprio(0);
    SBAR();
    // ================= P4: MFMA(ah1,b0) [all-reg]; stage B(t+2,h1) =======
    stB(t + 2, 1);
    if (t < 62) {
      asm volatile("s_waitcnt vmcnt(6)" ::: "memory");
    } else if (t == 62) {
      asm volatile("s_waitcnt vmcnt(0)" ::: "memory");
    }
    SCHED0();
    __builtin_amdgcn_s_setprio(1);
#pragma unroll
    for (int mq = 0; mq < 4; ++mq)
#pragma unroll
      for (int nq = 0; nq < 2; ++nq)
#pragma unroll
        for (int ks = 0; ks < 2; ++ks)
          MFMA16(a[mq][ks], b0[nq][ks], acc[4 + mq][nq]);
    __builtin_amdgcn_s_setprio(0);
    SBAR();

    // ---- inline LSTM epilogue at group end (regs+global only) ----
    if ((t & 15) == 15) {
      const int g = t >> 4;
#pragma unroll
      for (int mf = 0; mf < 8; ++mf) {
        const int grow0 = ((bmg << 2) + g) * 256 + (mf >> 2) * 128 + wm * 64 +
                          (mf & 3) * 16 + fg * 4;
#pragma unroll
        for (int j = 0; j < 4; ++j) {
          const size_t off = (size_t)(grow0 + j) * HDIM + np;
          float i_ = fsigmoid(acc[mf][0][j] + bi);
          float f_ = fsigmoid(acc[mf][1][j] + bf_);
          float g_ = fsigmoid(acc[mf][2][j] + bg);
          float o_ = fsigmoid(acc[mf][3][j] + bo);
          float cp = f_ * cin[off] + i_ * g_;
          out[off] = o_ * ftanh(cp);
          out[couts + off] = cp;
        }
#pragma unroll
        for (int n = 0; n < 4; ++n) acc[mf][n] = (f32x4){0.f, 0.f, 0.f, 0.f};
      }
    }
  }
}

// ====================== launch ======================
extern "C" void kernel_launch(void* const* d_in, const int* in_sizes, int n_in,
                              void* d_out, int out_size, void* d_ws,
                              size_t ws_size, hipStream_t stream) {
  const float* xin = (const float*)d_in[0];
  const float* hin = (const float*)d_in[1];
  const float* cin = (const float*)d_in[2];
  WPtrs wp;
  wp.wi[0] = (const float*)d_in[3];
  wp.wi[1] = (const float*)d_in[7];
  wp.wi[2] = (const float*)d_in[11];
  wp.wi[3] = (const float*)d_in[15];
  wp.wh[0] = (const float*)d_in[4];
  wp.wh[1] = (const float*)d_in[8];
  wp.wh[2] = (const float*)d_in[12];
  wp.wh[3] = (const float*)d_in[16];
  BPtrs bp;
  bp.bi[0] = (const float*)d_in[5];
  bp.bi[1] = (const float*)d_in[9];
  bp.bi[2] = (const float*)d_in[13];
  bp.bi[3] = (const float*)d_in[17];
  bp.bh[0] = (const float*)d_in[6];
  bp.bh[1] = (const float*)d_in[10];
  bp.bh[2] = (const float*)d_in[14];
  bp.bh[3] = (const float*)d_in[18];

  const size_t needA = (size_t)NB * KDIM * 2;    // 64 MiB
  const size_t needW = (size_t)2048 * KDIM * 2;  // 4 MiB

  __bf16* Abf = (__bf16*)d_ws;
  __bf16* Wt = (__bf16*)((char*)d_ws + needA);
  float* bias = (float*)((char*)d_ws + needA + needW);

  conv_a_kernel<<<2048, 256, 0, stream>>>(xin, hin, Abf);
  pack_w2_kernel<<<dim3(16, 8, 4), 256, 0, stream>>>(wp, Wt);
  pack_bias_kernel<<<8, 256, 0, stream>>>(bp, bias);
  lstm_gemm4<<<256, 512, 0, stream>>>(Abf, Wt, cin, bias, (float*)d_out);
}

// Round 5
// 205.601 us; speedup vs baseline: 1.7693x; 1.0247x over previous
//
#include <hip/hip_runtime.h>
#include <hip/hip_bf16.h>

typedef __attribute__((ext_vector_type(8))) __bf16 bf16x8;
typedef __attribute__((ext_vector_type(4))) float f32x4;

#define NB 32768
#define HDIM 512
#define KDIM 1024

struct WPtrs { const float* wi[4]; const float* wh[4]; };
struct BPtrs { const float* bi[4]; const float* bh[4]; };

__device__ __forceinline__ float fsigmoid(float x) {
  return 1.0f / (1.0f + __expf(-x));
}
__device__ __forceinline__ float ftanh(float x) {
  return 2.0f / (1.0f + __expf(-2.0f * x)) - 1.0f;
}
__device__ __forceinline__ bf16x8 pack8(float4 a, float4 b) {
  bf16x8 r;
  r[0] = (__bf16)a.x; r[1] = (__bf16)a.y; r[2] = (__bf16)a.z; r[3] = (__bf16)a.w;
  r[4] = (__bf16)b.x; r[5] = (__bf16)b.y; r[6] = (__bf16)b.z; r[7] = (__bf16)b.w;
  return r;
}
__device__ __forceinline__ void gll16(const void* g, void* l) {
  __builtin_amdgcn_global_load_lds(
      (const __attribute__((address_space(1))) void*)g,
      (__attribute__((address_space(3))) void*)l, 16, 0, 0);
}
#define MFMA16(A, B, C) \
  C = __builtin_amdgcn_mfma_f32_16x16x32_bf16(A, B, C, 0, 0, 0)
#define SBAR() __builtin_amdgcn_s_barrier()
#define SCHED0() __builtin_amdgcn_sched_barrier(0)

// ====================== prep ======================
__global__ void pack_bias_kernel(BPtrs p, float* __restrict__ bias) {
  int idx = blockIdx.x * 256 + threadIdx.x;  // 0..2047
  int g = idx >> 9, np = idx & 511;
  bias[idx] = p.bi[g][np] + p.bh[g][np];
}

// A = [x | h] -> bf16 [32768][1024]
__global__ void conv_a_kernel(const float* __restrict__ x,
                              const float* __restrict__ h,
                              __bf16* __restrict__ Abf) {
  const size_t N8 = (size_t)NB * KDIM / 8;
  for (size_t i = (size_t)blockIdx.x * blockDim.x + threadIdx.x; i < N8;
       i += (size_t)gridDim.x * blockDim.x) {
    size_t e = i * 8;
    int k = (int)(e & (KDIM - 1));
    size_t r = e >> 10;
    const float* s = (k < 512) ? (x + r * 512 + k) : (h + r * 512 + (k - 512));
    float4 v0 = *(const float4*)s;
    float4 v1 = *(const float4*)(s + 4);
    *(bf16x8*)(Abf + e) = pack8(v0, v1);
  }
}

// Wt[p][k], p(np,g) = (np>>6)*256 + (g>>1)*128 + ((np>>4)&3)*32 + (g&1)*16 + (np&15)
__global__ void pack_w2_kernel(WPtrs p, __bf16* __restrict__ Wt) {
  __shared__ float tile[64][65];
  const int kt = blockIdx.x;  // 16 k-tiles of 64
  const int nt = blockIdx.y;  // 8 np-tiles of 64
  const int g = blockIdx.z;   // gate
  const int k0 = kt * 64, n0 = nt * 64;
  const float* src = (k0 < 512) ? p.wi[g] : p.wh[g];
  const int k0l = (k0 < 512) ? k0 : (k0 - 512);
  const int rr = threadIdx.x >> 6;
  const int cc = threadIdx.x & 63;
#pragma unroll
  for (int pp = 0; pp < 16; ++pp) {
    int kk = pp * 4 + rr;
    tile[kk][cc] = src[(size_t)(k0l + kk) * 512 + (n0 + cc)];
  }
  __syncthreads();
#pragma unroll
  for (int pp = 0; pp < 16; ++pp) {
    int nn = pp * 4 + rr;
    int np = n0 + nn;
    int prow = (np >> 6) * 256 + ((g >> 1) << 7) + (((np >> 4) & 3) << 5) +
               ((g & 1) << 4) + (np & 15);
    Wt[(size_t)prow * KDIM + (k0 + cc)] = (__bf16)tile[cc][nn];
  }
}

// ====================== persistent main: ONE barrier per K-tile ======================
// LDS hazard audit (buffers: cb = t&1 read during tile t; stages in tile t
// write ONLY cb^1, holding tile t+1's data):
//   - all ds_reads of tile t hit cb; retired before the lgkmcnt(0) preceding
//     Q3's MFMA (last LDS-dependent cluster) -> all done before tile-end SBAR.
//   - gll writes of tile t target cb^1; its readers run in tile t+1, i.e.
//     after the SBAR; writes complete per-wave at vmcnt(0) before Q4, and
//     every wave executes that vmcnt before arriving at the SBAR -> any data
//     read after the SBAR is globally complete.
//   - stages of tile t+1 (writing cb) issue only after the SBAR, which
//     postdates every tile-t read of cb.
__global__ __launch_bounds__(512, 1) void lstm_gemm5(
    const __bf16* __restrict__ Abf, const __bf16* __restrict__ Wt,
    const float* __restrict__ cin, const float* __restrict__ bias,
    float* __restrict__ out) {
  __shared__ alignas(16) char lds[131072];
  const int tid = threadIdx.x;
  const int wid = tid >> 6;
  const int wm = wid >> 2, wn = wid & 3;
  const int lane = tid & 63;
  const int fc = lane & 15, fg = lane >> 4;

  const int bn = blockIdx.x & 7;    // one bn-panel per XCD (B stays L2-hot)
  const int bmg = blockIdx.x >> 3;  // 0..31, each covers 4 x 256 rows

  const __bf16* Bsrc = Wt + (size_t)bn * 256 * KDIM;

  const int r0 = tid >> 3;                     // 0..63
  const int ssl = ((tid & 7) ^ (r0 & 7)) * 8;  // inverse-swizzled k-slot
  const uint32_t ldst0 = (uint32_t)(tid >> 6) * 1024;

  f32x4 acc[8][4];
#pragma unroll
  for (int m = 0; m < 8; ++m)
#pragma unroll
    for (int n = 0; n < 4; ++n) acc[m][n] = (f32x4){0.f, 0.f, 0.f, 0.f};

  bf16x8 a[4][2], b0[2][2], b1[2][2];

  auto stA = [&](int t, int h) {
    if (t < 64) {
      const __bf16* g = Abf +
                        ((size_t)((bmg << 2) + (t >> 4)) * 256 + h * 128 + r0) *
                            KDIM +
                        (t & 15) * 64 + ssl;
      uint32_t lb = (uint32_t)(t & 1) * 65536 + (uint32_t)h * 16384 + ldst0;
      gll16(g, (void*)&lds[lb]);
      gll16(g + (size_t)64 * KDIM, (void*)&lds[lb + 8192]);
    }
  };
  auto stB = [&](int t, int h) {
    if (t < 64) {
      const __bf16* g =
          Bsrc + ((size_t)h * 128 + r0) * KDIM + (t & 15) * 64 + ssl;
      uint32_t lb =
          (uint32_t)(t & 1) * 65536 + 32768 + (uint32_t)h * 16384 + ldst0;
      gll16(g, (void*)&lds[lb]);
      gll16(g + (size_t)64 * KDIM, (void*)&lds[lb + 8192]);
    }
  };
  auto ldA = [&](int cb, int h, int mq, int ks) -> bf16x8 {
    int row = wm * 64 + mq * 16 + fc;
    uint32_t off = (uint32_t)cb * 65536 + (uint32_t)h * 16384 +
                   (uint32_t)row * 128 +
                   (uint32_t)(((ks * 4 + fg) ^ (row & 7)) << 4);
    return *(const bf16x8*)&lds[off];
  };
  auto ldB = [&](int cb, int h, int nq, int ks) -> bf16x8 {
    int row = wn * 32 + nq * 16 + fc;
    uint32_t off = (uint32_t)cb * 65536 + 32768 + (uint32_t)h * 16384 +
                   (uint32_t)row * 128 +
                   (uint32_t)(((ks * 4 + fg) ^ (row & 7)) << 4);
    return *(const bf16x8*)&lds[off];
  };

  // hoisted epilogue constants
  const int np = bn * 64 + wn * 16 + fc;
  const float bi = bias[np];
  const float bf_ = bias[512 + np];
  const float bg = bias[1024 + np];
  const float bo = bias[1536 + np];
  const size_t couts = (size_t)NB * HDIM;

  // prologue: stage tile 0 only (4 half-tiles), drain, barrier
  stA(0, 0); stA(0, 1); stB(0, 0); stB(0, 1);
  asm volatile("s_waitcnt vmcnt(0)" ::: "memory");
  SBAR();

#pragma unroll 2
  for (int t = 0; t < 64; ++t) {
    const int cb = t & 1;
    // ---- issue all 16 tile-reads: b0(4), ah0(8), b1(4); stage A(t+1) ----
#pragma unroll
    for (int nq = 0; nq < 2; ++nq)
#pragma unroll
      for (int ks = 0; ks < 2; ++ks) b0[nq][ks] = ldB(cb, 0, nq, ks);
#pragma unroll
    for (int mq = 0; mq < 4; ++mq)
#pragma unroll
      for (int ks = 0; ks < 2; ++ks) a[mq][ks] = ldA(cb, 0, mq, ks);
#pragma unroll
    for (int nq = 0; nq < 2; ++nq)
#pragma unroll
      for (int ks = 0; ks < 2; ++ks) b1[nq][ks] = ldB(cb, 1, nq, ks);
    stA(t + 1, 0);
    stA(t + 1, 1);
    // ---- Q1: MFMA(ah0,b0) ----
    asm volatile("s_waitcnt lgkmcnt(8)" ::: "memory");  // b0 + a[0..1]
    SCHED0();
    __builtin_amdgcn_s_setprio(1);
#pragma unroll
    for (int mq = 0; mq < 2; ++mq)
#pragma unroll
      for (int nq = 0; nq < 2; ++nq)
#pragma unroll
        for (int ks = 0; ks < 2; ++ks)
          MFMA16(a[mq][ks], b0[nq][ks], acc[mq][nq]);
    __builtin_amdgcn_s_setprio(0);
    asm volatile("s_waitcnt lgkmcnt(4)" ::: "memory");  // a[2..3]
    SCHED0();
    __builtin_amdgcn_s_setprio(1);
#pragma unroll
    for (int mq = 2; mq < 4; ++mq)
#pragma unroll
      for (int nq = 0; nq < 2; ++nq)
#pragma unroll
        for (int ks = 0; ks < 2; ++ks)
          MFMA16(a[mq][ks], b0[nq][ks], acc[mq][nq]);
    __builtin_amdgcn_s_setprio(0);
    stB(t + 1, 0);
    // ---- Q2: MFMA(ah0,b1) ----
    asm volatile("s_waitcnt lgkmcnt(0)" ::: "memory");  // b1
    SCHED0();
    __builtin_amdgcn_s_setprio(1);
#pragma unroll
    for (int mq = 0; mq < 4; ++mq)
#pragma unroll
      for (int nq = 0; nq < 2; ++nq)
#pragma unroll
        for (int ks = 0; ks < 2; ++ks)
          MFMA16(a[mq][ks], b1[nq][ks], acc[mq][2 + nq]);
    __builtin_amdgcn_s_setprio(0);
    // reload a <- A-h1 (8 reads; drains under Q2 tail / Q3 head)
#pragma unroll
    for (int mq = 0; mq < 4; ++mq)
#pragma unroll
      for (int ks = 0; ks < 2; ++ks) a[mq][ks] = ldA(cb, 1, mq, ks);
    stB(t + 1, 1);
    // ---- Q3: MFMA(ah1,b1) ----
    asm volatile("s_waitcnt lgkmcnt(4)" ::: "memory");  // a[0..1]
    SCHED0();
    __builtin_amdgcn_s_setprio(1);
#pragma unroll
    for (int mq = 0; mq < 2; ++mq)
#pragma unroll
      for (int nq = 0; nq < 2; ++nq)
#pragma unroll
        for (int ks = 0; ks < 2; ++ks)
          MFMA16(a[mq][ks], b1[nq][ks], acc[4 + mq][2 + nq]);
    __builtin_amdgcn_s_setprio(0);
    asm volatile("s_waitcnt lgkmcnt(0)" ::: "memory");  // a[2..3]
    SCHED0();
    __builtin_amdgcn_s_setprio(1);
#pragma unroll
    for (int mq = 2; mq < 4; ++mq)
#pragma unroll
      for (int nq = 0; nq < 2; ++nq)
#pragma unroll
        for (int ks = 0; ks < 2; ++ks)
          MFMA16(a[mq][ks], b1[nq][ks], acc[4 + mq][2 + nq]);
    __builtin_amdgcn_s_setprio(0);
    // ---- Q4: MFMA(ah1,b0) [all-register]; per-wave stage drain ----
    asm volatile("s_waitcnt vmcnt(0)" ::: "memory");  // t+1 stages complete
    __builtin_amdgcn_s_setprio(1);
#pragma unroll
    for (int mq = 0; mq < 4; ++mq)
#pragma unroll
      for (int nq = 0; nq < 2; ++nq)
#pragma unroll
        for (int ks = 0; ks < 2; ++ks)
          MFMA16(a[mq][ks], b0[nq][ks], acc[4 + mq][nq]);
    __builtin_amdgcn_s_setprio(0);
    SBAR();  // single barrier per K-tile

    // ---- inline LSTM epilogue at group end (regs+global only, no LDS) ----
    if ((t & 15) == 15) {
      const int g = t >> 4;
#pragma unroll
      for (int mf = 0; mf < 8; ++mf) {
        const int grow0 = ((bmg << 2) + g) * 256 + (mf >> 2) * 128 + wm * 64 +
                          (mf & 3) * 16 + fg * 4;
#pragma unroll
        for (int j = 0; j < 4; ++j) {
          const size_t off = (size_t)(grow0 + j) * HDIM + np;
          float i_ = fsigmoid(acc[mf][0][j] + bi);
          float f_ = fsigmoid(acc[mf][1][j] + bf_);
          float g_ = fsigmoid(acc[mf][2][j] + bg);
          float o_ = fsigmoid(acc[mf][3][j] + bo);
          float cp = f_ * cin[off] + i_ * g_;
          out[off] = o_ * ftanh(cp);
          out[couts + off] = cp;
        }
#pragma unroll
        for (int n = 0; n < 4; ++n) acc[mf][n] = (f32x4){0.f, 0.f, 0.f, 0.f};
      }
    }
  }
}

// ====================== launch ======================
extern "C" void kernel_launch(void* const* d_in, const int* in_sizes, int n_in,
                              void* d_out, int out_size, void* d_ws,
                              size_t ws_size, hipStream_t stream) {
  const float* xin = (const float*)d_in[0];
  const float* hin = (const float*)d_in[1];
  const float* cin = (const float*)d_in[2];
  WPtrs wp;
  wp.wi[0] = (const float*)d_in[3];
  wp.wi[1] = (const float*)d_in[7];
  wp.wi[2] = (const float*)d_in[11];
  wp.wi[3] = (const float*)d_in[15];
  wp.wh[0] = (const float*)d_in[4];
  wp.wh[1] = (const float*)d_in[8];
  wp.wh[2] = (const float*)d_in[12];
  wp.wh[3] = (const float*)d_in[16];
  BPtrs bp;
  bp.bi[0] = (const float*)d_in[5];
  bp.bi[1] = (const float*)d_in[9];
  bp.bi[2] = (const float*)d_in[13];
  bp.bi[3] = (const float*)d_in[17];
  bp.bh[0] = (const float*)d_in[6];
  bp.bh[1] = (const float*)d_in[10];
  bp.bh[2] = (const float*)d_in[14];
  bp.bh[3] = (const float*)d_in[18];

  const size_t needA = (size_t)NB * KDIM * 2;    // 64 MiB
  const size_t needW = (size_t)2048 * KDIM * 2;  // 4 MiB

  __bf16* Abf = (__bf16*)d_ws;
  __bf16* Wt = (__bf16*)((char*)d_ws + needA);
  float* bias = (float*)((char*)d_ws + needA + needW);

  conv_a_kernel<<<2048, 256, 0, stream>>>(xin, hin, Abf);
  pack_w2_kernel<<<dim3(16, 8, 4), 256, 0, stream>>>(wp, Wt);
  pack_bias_kernel<<<8, 256, 0, stream>>>(bp, bias);
  lstm_gemm5<<<256, 512, 0, stream>>>(Abf, Wt, cin, bias, (float*)d_out);
}